// Round 2
// baseline (2142.573 us; speedup 1.0000x reference)
//
#include <hip/hip_runtime.h>
#include <math.h>

#define NN   13
#define HH   128
#define K2   256
#define NL   8
#define NJ   17
#define OBSD 348
#define DMAX 33
#define TB   8
#define NTHR 256

// FEAT_IDX table (13 x 33), pad = -1 (maps to the zero column of obs_ext)
__constant__ int c_feat[NN * DMAX] = {
  // node 0 (33)
  0,1,2,3,4,22,23,24,25,26,27,45,46,47,48,49,50,51,52,53,54,175,176,177,178,179,180,270,271,272,273,274,275,
  // node 1 (26)
  5,6,28,29,55,56,57,58,59,60,61,62,63,64,181,182,183,184,185,186,276,277,278,279,280,281,-1,-1,-1,-1,-1,-1,-1,
  // node 2 (27)
  7,30,65,66,67,68,69,70,71,72,73,74,187,188,189,190,191,192,253,254,255,282,283,284,285,286,287,-1,-1,-1,-1,-1,-1,
  // node 3 (33)
  8,9,10,11,31,32,33,34,75,76,77,78,79,80,81,82,83,84,193,194,195,196,197,198,256,257,258,288,289,290,291,292,293,
  // node 4 (25)
  11,34,85,86,87,88,89,90,91,92,93,94,199,200,201,202,203,204,259,294,295,296,297,298,299,-1,-1,-1,-1,-1,-1,-1,-1,
  // node 5 (22)
  95,96,97,98,99,100,101,102,103,104,205,206,207,208,209,210,300,301,302,303,304,305,-1,-1,-1,-1,-1,-1,-1,-1,-1,-1,-1,
  // node 6 (33)
  12,13,14,15,35,36,37,38,105,106,107,108,109,110,111,112,113,114,211,212,213,214,215,216,260,261,262,306,307,308,309,310,311,
  // node 7 (25)
  15,38,115,116,117,118,119,120,121,122,123,124,217,218,219,220,221,222,263,312,313,314,315,316,317,-1,-1,-1,-1,-1,-1,-1,-1,
  // node 8 (22)
  125,126,127,128,129,130,131,132,133,134,223,224,225,226,227,228,318,319,320,321,322,323,-1,-1,-1,-1,-1,-1,-1,-1,-1,-1,-1,
  // node 9 (30)
  16,17,18,39,40,41,135,136,137,138,139,140,141,142,143,144,229,230,231,232,233,234,264,265,324,325,326,327,328,329,-1,-1,-1,
  // node 10 (25)
  18,41,145,146,147,148,149,150,151,152,153,154,235,236,237,238,239,240,266,330,331,332,333,334,335,-1,-1,-1,-1,-1,-1,-1,-1,
  // node 11 (30)
  19,20,21,42,43,44,155,156,157,158,159,160,161,162,163,164,241,242,243,244,245,246,267,268,336,337,338,339,340,341,-1,-1,-1,
  // node 12 (25)
  21,44,165,166,167,168,169,170,171,172,173,174,247,248,249,250,251,252,269,342,343,344,345,346,347,-1,-1,-1,-1,-1,-1,-1,-1
};

// undirected adjacency (neighbors), compile-time foldable
__device__ constexpr int ADJ[NN][3] = {
  {1,9,11},{0,2,0},{1,3,6},{2,4,0},{3,5,0},{4,0,0},{2,7,0},
  {6,8,0},{7,0,0},{0,10,0},{9,0,0},{0,12,0},{11,0,0}
};
__device__ constexpr int DEG[NN] = {3,2,3,2,2,1,2,2,1,2,1,2,1};
__device__ constexpr int JM0[NJ] = {1,1,1,2,2,2,3,2,2,2,6,0,0,9,0,0,11};
__device__ constexpr int JM1[NJ] = {2,2,2,3,3,3,4,6,6,6,7,9,9,10,11,11,12};

typedef float4 F4;

__device__ __forceinline__ float elu1(float v) {
  return v > 0.0f ? v : expm1f(v);
}

__global__ __launch_bounds__(NTHR, 1)
void gnn_fused(const float* __restrict__ obs,
               const float* __restrict__ W1, const float* __restrict__ b1,
               const float* __restrict__ W2, const float* __restrict__ b2,
               const float* __restrict__ Wm, const float* __restrict__ bm,
               const float* __restrict__ Wo, const float* __restrict__ bo,
               float* __restrict__ out)
{
  // xs[TB][NN][256]: per-batch-element node state, [0:128)=x, [128:256)=agg/h
  __shared__ float xs[TB * NN * K2];      // 104 KB
  // wb: two ping-pong 32-row Wmsg chunks (2 x 16 KB); buf0 doubles as the
  // xn gather buffer [TB][NN][36] (3744 floats < 4096) in phase 0/1.
  __shared__ float wb[2 * 32 * HH];       // 32 KB  -> 136 KB total

  const int t  = threadIdx.x;
  const int bl = t >> 5;        // batch-local 0..7 (32-thread group; wave = 2 groups)
  const int og = t & 31;        // channel group
  const int o0 = og << 2;       // 4 channels per thread
  const int b0 = blockIdx.x * TB;

  F4* xsv  = (F4*)xs;
  F4* bufA = (F4*)wb;           // 1024 float4
  F4* bufB = ((F4*)wb) + 1024;

  // ---------- Phase 0: gather xn into wb (cross-wave -> barrier after) ----------
  for (int i = t; i < TB * NN * DMAX; i += NTHR) {
    int d  = i % DMAX;
    int r  = i / DMAX;
    int nn = r % NN;
    int bb = r / NN;
    int fi = c_feat[nn * DMAX + d];
    float v = (fi >= 0) ? obs[(b0 + bb) * OBSD + fi] : 0.0f;
    wb[(bb * NN + nn) * 36 + d] = v;
  }
  __syncthreads();

  // ---------- Phase 1: h = elu(xn @ W1 + b1) -> xs[...][128:256) ----------
  // thread group = (node, 4 channels), loops all 8 batch elems (weight reuse x8)
  #pragma unroll
  for (int pass = 0; pass < 2; ++pass) {
    const int n = (t >> 5) + pass * 8;
    if (n < NN) {
      float acc[TB][4];
      const F4 bv = *(const F4*)(b1 + n * HH + o0);
      #pragma unroll
      for (int q = 0; q < TB; ++q) {
        acc[q][0] = bv.x; acc[q][1] = bv.y; acc[q][2] = bv.z; acc[q][3] = bv.w;
      }
      #pragma unroll 3
      for (int k = 0; k < DMAX; ++k) {
        const F4 w = *(const F4*)(W1 + (n * DMAX + k) * HH + o0);
        #pragma unroll
        for (int q = 0; q < TB; ++q) {
          const float xv = wb[(q * NN + n) * 36 + k];
          acc[q][0] += xv * w.x; acc[q][1] += xv * w.y;
          acc[q][2] += xv * w.z; acc[q][3] += xv * w.w;
        }
      }
      #pragma unroll
      for (int q = 0; q < TB; ++q) {
        F4 h;
        h.x = elu1(acc[q][0]); h.y = elu1(acc[q][1]);
        h.z = elu1(acc[q][2]); h.w = elu1(acc[q][3]);
        *(F4*)(xs + (q * NN + n) * K2 + HH + o0) = h;
      }
    }
  }
  // NO barrier: phase 2's group n reads exactly the rows written by the same
  // 32-thread group here (intra-wave LDS RAW; compiler inserts lgkmcnt).

  // ---------- Phase 2: x = h @ W2 + b2 -> xs[...][0:128)  (no ELU) ----------
  #pragma unroll
  for (int pass = 0; pass < 2; ++pass) {
    const int n = (t >> 5) + pass * 8;
    if (n < NN) {
      float acc[TB][4];
      const F4 bv = *(const F4*)(b2 + n * HH + o0);
      #pragma unroll
      for (int q = 0; q < TB; ++q) {
        acc[q][0] = bv.x; acc[q][1] = bv.y; acc[q][2] = bv.z; acc[q][3] = bv.w;
      }
      #pragma unroll 4
      for (int k = 0; k < HH; ++k) {
        const F4 w = *(const F4*)(W2 + (n * HH + k) * HH + o0);
        #pragma unroll
        for (int q = 0; q < TB; ++q) {
          const float hv = xs[(q * NN + n) * K2 + HH + k];
          acc[q][0] += hv * w.x; acc[q][1] += hv * w.y;
          acc[q][2] += hv * w.z; acc[q][3] += hv * w.w;
        }
      }
      #pragma unroll
      for (int q = 0; q < TB; ++q) {
        F4 v;
        v.x = acc[q][0]; v.y = acc[q][1]; v.z = acc[q][2]; v.w = acc[q][3];
        *(F4*)(xs + (q * NN + n) * K2 + o0) = v;
      }
    }
  }
  __syncthreads();  // phase 3 uses bl-mapping: cross-wave handoff of xs

  // ---------- Phase 3: 8 message-passing layers ----------
  // Wmsg streamed as 64 chunks of 32 rows (16 KB), ping-pong double-buffered.
  // Chunk g+1 is loaded to REGISTERS, compute on chunk g runs (hiding the
  // global latency), regs stored to LDS, one barrier per chunk.
  {
    const F4* wsrc = (const F4*)Wm;
    // prologue: stage chunk 0
    bufA[t] = wsrc[t]; bufA[t + 256] = wsrc[t + 256];
    bufA[t + 512] = wsrc[t + 512]; bufA[t + 768] = wsrc[t + 768];
    __syncthreads();

    for (int l = 0; l < NL; ++l) {
      // agg: xs[bl][n][128+c] = sum over neighbors of xs[bl][n'][c]
      // (entirely intra-wave: this group wrote these x rows)
      {
        const int rowb = bl * NN;
        #pragma unroll
        for (int n = 0; n < NN; ++n) {
          F4 s = xsv[(rowb + ADJ[n][0]) * 64 + og];
          if (DEG[n] > 1) {
            F4 u = xsv[(rowb + ADJ[n][1]) * 64 + og];
            s.x += u.x; s.y += u.y; s.z += u.z; s.w += u.w;
          }
          if (DEG[n] > 2) {
            F4 u = xsv[(rowb + ADJ[n][2]) * 64 + og];
            s.x += u.x; s.y += u.y; s.z += u.z; s.w += u.w;
          }
          xsv[(rowb + n) * 64 + 32 + og] = s;
        }
      }

      float acc[NN][4];
      {
        const F4 bv = *(const F4*)(bm + l * HH + o0);
        #pragma unroll
        for (int n = 0; n < NN; ++n) {
          acc[n][0] = bv.x; acc[n][1] = bv.y; acc[n][2] = bv.z; acc[n][3] = bv.w;
        }
      }

      for (int c = 0; c < 8; ++c) {
        const int g = l * 8 + c;          // global chunk index, 0..63
        F4* cur = (g & 1) ? bufB : bufA;
        F4* nxt = (g & 1) ? bufA : bufB;

        // issue next chunk's global loads into registers (latency hidden by compute)
        F4 r0, r1, r2, r3;
        const bool more = (g < NL * 8 - 1);
        if (more) {
          const F4* s = wsrc + (size_t)(g + 1) * 1024;
          r0 = s[t]; r1 = s[t + 256]; r2 = s[t + 512]; r3 = s[t + 768];
        }

        // compute: k-range [c*32, c*32+32)
        const int xbase = (bl * NN) * 64 + c * 8;   // float4 offset of k-slice
        #pragma unroll 2
        for (int k4 = 0; k4 < 8; ++k4) {
          const F4 w0 = cur[(k4 * 4 + 0) * 32 + og];
          const F4 w1 = cur[(k4 * 4 + 1) * 32 + og];
          const F4 w2 = cur[(k4 * 4 + 2) * 32 + og];
          const F4 w3 = cur[(k4 * 4 + 3) * 32 + og];
          #pragma unroll
          for (int n = 0; n < NN; ++n) {
            const F4 xv = xsv[xbase + n * 64 + k4];
            acc[n][0] += xv.x * w0.x; acc[n][0] += xv.y * w1.x;
            acc[n][0] += xv.z * w2.x; acc[n][0] += xv.w * w3.x;
            acc[n][1] += xv.x * w0.y; acc[n][1] += xv.y * w1.y;
            acc[n][1] += xv.z * w2.y; acc[n][1] += xv.w * w3.y;
            acc[n][2] += xv.x * w0.z; acc[n][2] += xv.y * w1.z;
            acc[n][2] += xv.z * w2.z; acc[n][2] += xv.w * w3.z;
            acc[n][3] += xv.x * w0.w; acc[n][3] += xv.y * w1.w;
            acc[n][3] += xv.z * w2.w; acc[n][3] += xv.w * w3.w;
          }
        }

        if (more) {
          nxt[t] = r0; nxt[t + 256] = r1; nxt[t + 512] = r2; nxt[t + 768] = r3;
        }
        __syncthreads();   // publishes nxt, and guards cur reuse next iteration
      }

      // x = elu(acc) -> xs first half (intra-wave consumers only)
      #pragma unroll
      for (int n = 0; n < NN; ++n) {
        F4 v;
        v.x = elu1(acc[n][0]); v.y = elu1(acc[n][1]);
        v.z = elu1(acc[n][2]); v.w = elu1(acc[n][3]);
        xsv[(bl * NN + n) * 64 + og] = v;
      }
    }
  }

  // ---------- Phase 4: readout out[b][j] (intra-wave reads, no barrier) ----------
  #pragma unroll
  for (int j = 0; j < NJ; ++j) {
    const F4 xa = xsv[(bl * NN + JM0[j]) * 64 + og];
    const F4 xb = xsv[(bl * NN + JM1[j]) * 64 + og];
    const F4 wa = *(const F4*)(Wo + j * K2 + o0);
    const F4 wc = *(const F4*)(Wo + j * K2 + HH + o0);
    float p = xa.x * wa.x + xa.y * wa.y + xa.z * wa.z + xa.w * wa.w
            + xb.x * wc.x + xb.y * wc.y + xb.z * wc.z + xb.w * wc.w;
    // reduce across the 32 lanes of this bl-group (xor offsets < 32 stay in-group)
    p += __shfl_xor(p, 16);
    p += __shfl_xor(p, 8);
    p += __shfl_xor(p, 4);
    p += __shfl_xor(p, 2);
    p += __shfl_xor(p, 1);
    if (og == 0)
      out[(b0 + bl) * NJ + j] = p + bo[j];
  }
}

extern "C" void kernel_launch(void* const* d_in, const int* in_sizes, int n_in,
                              void* d_out, int out_size, void* d_ws, size_t ws_size,
                              hipStream_t stream) {
  const float* obs = (const float*)d_in[0];
  const float* W1  = (const float*)d_in[1];
  const float* b1  = (const float*)d_in[2];
  const float* W2  = (const float*)d_in[3];
  const float* b2  = (const float*)d_in[4];
  const float* Wm  = (const float*)d_in[5];
  const float* bm  = (const float*)d_in[6];
  const float* Wo  = (const float*)d_in[7];
  const float* bo  = (const float*)d_in[8];
  float* out = (float*)d_out;

  const int B = in_sizes[0] / OBSD;   // 16384
  const int nblk = B / TB;            // 2048

  gnn_fused<<<nblk, NTHR, 0, stream>>>(obs, W1, b1, W2, b2, Wm, bm, Wo, bo, out);
}

// Round 3
// 1142.160 us; speedup vs baseline: 1.8759x; 1.8759x over previous
//
#include <hip/hip_runtime.h>
#include <math.h>

#define NN   13
#define HH   128
#define NL   8
#define NJ   17
#define OBSD 348
#define DMAX 33
#define TB   8
#define NTHR 256
#define ASTRIDE 264   // shorts per A-plane row (16 octets * 16 + 8 pad) = 528 B
#define HSTRIDE 132   // same 528 B row viewed as fp32 (h scratch)

// FEAT_IDX table (13 x 33), pad = -1
__constant__ int c_feat[NN * DMAX] = {
  0,1,2,3,4,22,23,24,25,26,27,45,46,47,48,49,50,51,52,53,54,175,176,177,178,179,180,270,271,272,273,274,275,
  5,6,28,29,55,56,57,58,59,60,61,62,63,64,181,182,183,184,185,186,276,277,278,279,280,281,-1,-1,-1,-1,-1,-1,-1,
  7,30,65,66,67,68,69,70,71,72,73,74,187,188,189,190,191,192,253,254,255,282,283,284,285,286,287,-1,-1,-1,-1,-1,-1,
  8,9,10,11,31,32,33,34,75,76,77,78,79,80,81,82,83,84,193,194,195,196,197,198,256,257,258,288,289,290,291,292,293,
  11,34,85,86,87,88,89,90,91,92,93,94,199,200,201,202,203,204,259,294,295,296,297,298,299,-1,-1,-1,-1,-1,-1,-1,-1,
  95,96,97,98,99,100,101,102,103,104,205,206,207,208,209,210,300,301,302,303,304,305,-1,-1,-1,-1,-1,-1,-1,-1,-1,-1,-1,
  12,13,14,15,35,36,37,38,105,106,107,108,109,110,111,112,113,114,211,212,213,214,215,216,260,261,262,306,307,308,309,310,311,
  15,38,115,116,117,118,119,120,121,122,123,124,217,218,219,220,221,222,263,312,313,314,315,316,317,-1,-1,-1,-1,-1,-1,-1,-1,
  125,126,127,128,129,130,131,132,133,134,223,224,225,226,227,228,318,319,320,321,322,323,-1,-1,-1,-1,-1,-1,-1,-1,-1,-1,-1,
  16,17,18,39,40,41,135,136,137,138,139,140,141,142,143,144,229,230,231,232,233,234,264,265,324,325,326,327,328,329,-1,-1,-1,
  18,41,145,146,147,148,149,150,151,152,153,154,235,236,237,238,239,240,266,330,331,332,333,334,335,-1,-1,-1,-1,-1,-1,-1,-1,
  19,20,21,42,43,44,155,156,157,158,159,160,161,162,163,164,241,242,243,244,245,246,267,268,336,337,338,339,340,341,-1,-1,-1,
  21,44,165,166,167,168,169,170,171,172,173,174,247,248,249,250,251,252,269,342,343,344,345,346,347,-1,-1,-1,-1,-1,-1,-1,-1
};

__device__ constexpr int ADJ[NN][3] = {
  {1,9,11},{0,2,0},{1,3,6},{2,4,0},{3,5,0},{4,0,0},{2,7,0},
  {6,8,0},{7,0,0},{0,10,0},{9,0,0},{0,12,0},{11,0,0}
};
__device__ constexpr int DEG[NN] = {3,2,3,2,2,1,2,2,1,2,1,2,1};
__device__ constexpr int JM0[NJ] = {1,1,1,2,2,2,3,2,2,2,6,0,0,9,0,0,11};
__device__ constexpr int JM1[NJ] = {2,2,2,3,3,3,4,6,6,6,7,9,9,10,11,11,12};

typedef float4 F4;
using s8v    = __attribute__((ext_vector_type(8)))  short;   // 8 bf16 (4 VGPR)
using f32x16 = __attribute__((ext_vector_type(16))) float;   // MFMA 32x32 C/D

__device__ __forceinline__ float elu1(float v) { return v > 0.0f ? v : expm1f(v); }

__device__ __forceinline__ unsigned short bf16r(float v) {   // round-to-nearest-even
  unsigned u = __float_as_uint(v);
  unsigned r = u + 0x7FFFu + ((u >> 16) & 1u);
  return (unsigned short)(r >> 16);
}
__device__ __forceinline__ float bf2f(unsigned short s) {
  return __uint_as_float(((unsigned)s) << 16);
}

// ---------------- pre-pass: split+swizzle Wmsg into frag-linear order -------
// ws u32 layout: [l(8)][ks(8)][kind(4: Thi,Tlo,Bhi,Blo)][nt(4)][lane(64)][j2(4)]
// value pair: k = ks*16 + (lane>>5)*8 + 2*j2 ; n = nt*32 + (lane&31)
__global__ void prep_wm(const float* __restrict__ Wm, unsigned* __restrict__ ws) {
  int i = blockIdx.x * 256 + threadIdx.x;      // 0 .. 524287
  int j2   = i & 3;
  int lane = (i >> 2) & 63;
  int nt   = (i >> 8) & 3;
  int kind = (i >> 10) & 3;
  int ks   = (i >> 12) & 7;
  int l    = i >> 15;
  int k = ks * 16 + ((lane >> 5) * 8) + 2 * j2;
  int n = nt * 32 + (lane & 31);
  int rbase = (kind >= 2) ? 128 : 0;           // bottom half of Wmsg rows = agg part
  float v0 = Wm[((l * 256) + rbase + k) * HH + n];
  float v1 = Wm[((l * 256) + rbase + k + 1) * HH + n];
  unsigned short a, b;
  if ((kind & 1) == 0) { a = bf16r(v0); b = bf16r(v1); }
  else {
    a = bf16r(v0 - bf2f(bf16r(v0)));
    b = bf16r(v1 - bf2f(bf16r(v1)));
  }
  ws[i] = (unsigned)a | ((unsigned)b << 16);
}

// ---------------- main fused kernel ----------------------------------------
__global__ __launch_bounds__(NTHR, 1)
void gnn_fused(const float* __restrict__ obs,
               const float* __restrict__ W1, const float* __restrict__ b1,
               const float* __restrict__ W2, const float* __restrict__ b2,
               const float* __restrict__ bm,
               const float* __restrict__ Wo, const float* __restrict__ bo,
               const float* __restrict__ wmsw,   // pre-swizzled Wmsg (as float4 stream)
               float* __restrict__ out)
{
  // A-planes: x state, 128 rows (elem*16+node) x [oct(16)][hi 8 | lo 8] bf16
  __shared__ short As[128 * ASTRIDE];          // 67584 B ; aliased as fp32 h scratch
  __shared__ float Bb[2][4096];                // 2 x 16 KB Wmsg ks-chunk ping-pong

  const int t    = threadIdx.x;
  const int wid  = t >> 6;        // wave 0..3
  const int mh   = wid >> 1;      // m-half (2 m-tiles)
  const int nh   = wid & 1;       // n-half (2 n-tiles)
  const int lane = t & 63;
  const int l31  = lane & 31;
  const int lh   = lane >> 5;     // k-half within frag / row-group bit in C
  const bool h1  = (lh == 1);
  const int g    = t >> 5;        // 32-thread group 0..7 (VALU phases: elem or node)
  const int og   = t & 31;
  const int o0   = og << 2;
  const int b0   = blockIdx.x * TB;

  const F4* wsrc4 = (const F4*)wmsw;
  float* hsc = (float*)As;        // h scratch (row stride HSTRIDE floats = 528 B)
  float* xnb = Bb[1];             // xn gather scratch (3744 floats < 4096)

  // ---------- Phase 0: stage Wmsg chunk0 -> Bb[0]; zero pad rows; gather xn --
  {
    F4* d = (F4*)Bb[0];
    #pragma unroll
    for (int i = 0; i < 4; ++i) d[t + i * 256] = wsrc4[t + i * 256];
  }
  for (int i = t; i < 24 * HSTRIDE; i += NTHR) {         // rows elem*16+{13,14,15}
    int pr = i / HSTRIDE, off = i % HSTRIDE;
    int row = (pr / 3) * 16 + 13 + (pr % 3);
    ((int*)As)[row * HSTRIDE + off] = 0;
  }
  for (int i = t; i < TB * NN * DMAX; i += NTHR) {
    int d  = i % DMAX;
    int r  = i / DMAX;
    int nn = r % NN;
    int bb = r / NN;
    int fi = c_feat[nn * DMAX + d];
    float v = (fi >= 0) ? obs[(b0 + bb) * OBSD + fi] : 0.0f;
    xnb[(bb * NN + nn) * 36 + d] = v;
  }
  __syncthreads();

  // ---------- Phase 1 (VALU): h = elu(xn @ W1 + b1) -> hsc fp32 -------------
  #pragma unroll
  for (int pass = 0; pass < 2; ++pass) {
    const int n = g + pass * 8;
    if (n < NN) {
      float acc[TB][4];
      const F4 bv = *(const F4*)(b1 + n * HH + o0);
      #pragma unroll
      for (int q = 0; q < TB; ++q) { acc[q][0]=bv.x; acc[q][1]=bv.y; acc[q][2]=bv.z; acc[q][3]=bv.w; }
      #pragma unroll 3
      for (int k = 0; k < DMAX; ++k) {
        const F4 w = *(const F4*)(W1 + (n * DMAX + k) * HH + o0);
        #pragma unroll
        for (int q = 0; q < TB; ++q) {
          const float xv = xnb[(q * NN + n) * 36 + k];
          acc[q][0] += xv * w.x; acc[q][1] += xv * w.y;
          acc[q][2] += xv * w.z; acc[q][3] += xv * w.w;
        }
      }
      #pragma unroll
      for (int q = 0; q < TB; ++q) {
        F4 h;
        h.x = elu1(acc[q][0]); h.y = elu1(acc[q][1]);
        h.z = elu1(acc[q][2]); h.w = elu1(acc[q][3]);
        *(F4*)&hsc[(q * 16 + n) * HSTRIDE + o0] = h;
      }
    }
  }
  __syncthreads();

  // ---------- Phase 2 (VALU): x = h @ W2 + b2 -> regs, then split-store ------
  float xacc[2][TB][4];     // [pass][elem][ch]
  #pragma unroll
  for (int pass = 0; pass < 2; ++pass) {
    const int n = g + pass * 8;
    if (n < NN) {
      const F4 bv = *(const F4*)(b2 + n * HH + o0);
      #pragma unroll
      for (int q = 0; q < TB; ++q) {
        xacc[pass][q][0]=bv.x; xacc[pass][q][1]=bv.y; xacc[pass][q][2]=bv.z; xacc[pass][q][3]=bv.w;
      }
      #pragma unroll 2
      for (int k4 = 0; k4 < 32; ++k4) {
        const F4 w0 = *(const F4*)(W2 + (n * HH + k4*4 + 0) * HH + o0);
        const F4 w1 = *(const F4*)(W2 + (n * HH + k4*4 + 1) * HH + o0);
        const F4 w2 = *(const F4*)(W2 + (n * HH + k4*4 + 2) * HH + o0);
        const F4 w3 = *(const F4*)(W2 + (n * HH + k4*4 + 3) * HH + o0);
        #pragma unroll
        for (int q = 0; q < TB; ++q) {
          const F4 hv = *(const F4*)&hsc[(q * 16 + n) * HSTRIDE + k4 * 4];
          xacc[pass][q][0] += hv.x*w0.x + hv.y*w1.x + hv.z*w2.x + hv.w*w3.x;
          xacc[pass][q][1] += hv.x*w0.y + hv.y*w1.y + hv.z*w2.y + hv.w*w3.y;
          xacc[pass][q][2] += hv.x*w0.z + hv.y*w1.z + hv.z*w2.z + hv.w*w3.z;
          xacc[pass][q][3] += hv.x*w0.w + hv.y*w1.w + hv.z*w2.w + hv.w*w3.w;
        }
      }
    }
  }
  __syncthreads();   // all h reads done; safe to overwrite As with x planes
  #pragma unroll
  for (int pass = 0; pass < 2; ++pass) {
    const int n = g + pass * 8;
    if (n < NN) {
      #pragma unroll
      for (int q = 0; q < TB; ++q) {
        #pragma unroll
        for (int cc = 0; cc < 4; ++cc) {
          float v = xacc[pass][q][cc];
          unsigned short hs = bf16r(v);
          unsigned short ls = bf16r(v - bf2f(hs));
          int col = o0 + cc;
          int ad  = (q * 16 + n) * ASTRIDE + ((col >> 3) << 4) + (col & 7);
          As[ad]     = (short)hs;
          As[ad + 8] = (short)ls;
        }
      }
    }
  }
  __syncthreads();

  // ---------- Phase 3: 8 MFMA layers ----------------------------------------
  #pragma unroll 1
  for (int l = 0; l < NL; ++l) {
    f32x16 aT[2][2], aB[2][2];
    #pragma unroll
    for (int mi = 0; mi < 2; ++mi)
      #pragma unroll
      for (int ni = 0; ni < 2; ++ni)
        #pragma unroll
        for (int r = 0; r < 16; ++r) { aT[mi][ni][r] = 0.f; aB[mi][ni][r] = 0.f; }

    #pragma unroll 1
    for (int ks = 0; ks < 8; ++ks) {
      const int chunk = l * 8 + ks;
      const bool more = (chunk < NL * 8 - 1);
      F4 p0, p1, p2, p3;
      if (more) {
        const F4* s = wsrc4 + (size_t)(chunk + 1) * 1024;
        p0 = s[t]; p1 = s[t + 256]; p2 = s[t + 512]; p3 = s[t + 768];
      }

      const short* bb = (const short*)Bb[ks & 1];
      s8v ah[2], al[2];
      #pragma unroll
      for (int mi = 0; mi < 2; ++mi) {
        const int row = (mh * 2 + mi) * 32 + l31;
        const short* ap = As + row * ASTRIDE + (2 * ks + lh) * 16;
        ah[mi] = *(const s8v*)ap;
        al[mi] = *(const s8v*)(ap + 8);
      }
      s8v bth[2], btl[2], bbh[2], bbl[2];
      #pragma unroll
      for (int ni = 0; ni < 2; ++ni) {
        const int ntab = nh * 2 + ni;
        bth[ni] = *(const s8v*)(bb + ((0 * 4 + ntab) * 64 + lane) * 8);
        btl[ni] = *(const s8v*)(bb + ((1 * 4 + ntab) * 64 + lane) * 8);
        bbh[ni] = *(const s8v*)(bb + ((2 * 4 + ntab) * 64 + lane) * 8);
        bbl[ni] = *(const s8v*)(bb + ((3 * 4 + ntab) * 64 + lane) * 8);
      }
      #pragma unroll
      for (int mi = 0; mi < 2; ++mi)
        #pragma unroll
        for (int ni = 0; ni < 2; ++ni) {
          aT[mi][ni] = __builtin_amdgcn_mfma_f32_32x32x16_bf16(ah[mi], bth[ni], aT[mi][ni], 0, 0, 0);
          aT[mi][ni] = __builtin_amdgcn_mfma_f32_32x32x16_bf16(ah[mi], btl[ni], aT[mi][ni], 0, 0, 0);
          aT[mi][ni] = __builtin_amdgcn_mfma_f32_32x32x16_bf16(al[mi], bth[ni], aT[mi][ni], 0, 0, 0);
          aB[mi][ni] = __builtin_amdgcn_mfma_f32_32x32x16_bf16(ah[mi], bbh[ni], aB[mi][ni], 0, 0, 0);
          aB[mi][ni] = __builtin_amdgcn_mfma_f32_32x32x16_bf16(ah[mi], bbl[ni], aB[mi][ni], 0, 0, 0);
          aB[mi][ni] = __builtin_amdgcn_mfma_f32_32x32x16_bf16(al[mi], bbh[ni], aB[mi][ni], 0, 0, 0);
        }

      if (more) {
        F4* d = (F4*)Bb[(ks + 1) & 1];
        d[t] = p0; d[t + 256] = p1; d[t + 512] = p2; d[t + 768] = p3;
      }
      __syncthreads();
    }

    // epilogue: x_new = elu(Y_top + N*Y_bot + bias) ; split-store to As
    #pragma unroll
    for (int mi = 0; mi < 2; ++mi) {
      #pragma unroll
      for (int ni = 0; ni < 2; ++ni) {
        const int col  = (nh * 2 + ni) * 32 + l31;
        const float bias = bm[l * HH + col];
        float cb[16], sw[16];
        #pragma unroll
        for (int r = 0; r < 16; ++r) { cb[r] = aB[mi][ni][r]; sw[r] = __shfl_xor(cb[r], 32); }

        #pragma unroll
        for (int r = 0; r < 16; ++r) {
          const int p  = (r & 3) + 8 * (r >> 2);
          const int n0 = p & 15;            // node for lane-half 0
          const int n1 = n0 + 4;            // node for lane-half 1 (may be pad)
          const int es = p >> 4;            // elem-sub within tile (h-independent)
          // source accessor: Y_bot value at (node np, elem-sub es), this col
          #define SRCV(np)                                                \
            ({ const int rl = (es << 4) + (np);                           \
               const int hp = (rl >> 2) & 1;                              \
               const int pp = rl - 4 * hp;                                \
               const int rp = (pp & 3) + 4 * (pp >> 3);                   \
               (hp == 1) ? (h1 ? cb[rp] : sw[rp])                         \
                         : (h1 ? sw[rp] : cb[rp]); })
          float a0 = SRCV(ADJ[n0][0]);
          if (DEG[n0] > 1) a0 += SRCV(ADJ[n0][1]);
          if (DEG[n0] > 2) a0 += SRCV(ADJ[n0][2]);
          float a1 = 0.f;
          if (n1 < NN) {
            a1 = SRCV(ADJ[n1][0]);
            if (DEG[n1] > 1) a1 += SRCV(ADJ[n1][1]);
            if (DEG[n1] > 2) a1 += SRCV(ADJ[n1][2]);
          }
          #undef SRCV
          const float agg = h1 ? a1 : a0;
          const float tot = aT[mi][ni][r] + agg + bias;
          float xv = elu1(tot);
          if (n1 >= NN) xv = h1 ? 0.f : xv;    // keep pad rows zero
          unsigned short hs = bf16r(xv);
          unsigned short ls = bf16r(xv - bf2f(hs));
          const int row = (mh * 2 + mi) * 32 + p + 4 * lh;
          const int ad  = row * ASTRIDE + ((col >> 3) << 4) + (col & 7);
          As[ad]     = (short)hs;
          As[ad + 8] = (short)ls;
        }
      }
    }
    __syncthreads();
  }

  // ---------- Phase 4: readout ----------------------------------------------
  {
    const int elem = g;          // 0..7
    const int c = og * 4;        // 4 channels per thread
    float xv[NN][4];
    #pragma unroll
    for (int n = 0; n < NN; ++n) {
      const int ad = (elem * 16 + n) * ASTRIDE + ((c >> 3) << 4) + (c & 7);
      const ushort4 uh = *(const ushort4*)(As + ad);
      const ushort4 ul = *(const ushort4*)(As + ad + 8);
      xv[n][0] = bf2f(uh.x) + bf2f(ul.x);
      xv[n][1] = bf2f(uh.y) + bf2f(ul.y);
      xv[n][2] = bf2f(uh.z) + bf2f(ul.z);
      xv[n][3] = bf2f(uh.w) + bf2f(ul.w);
    }
    #pragma unroll
    for (int j = 0; j < NJ; ++j) {
      const F4 wa = *(const F4*)(Wo + j * 256 + c);
      const F4 wb = *(const F4*)(Wo + j * 256 + 128 + c);
      const float* xa = xv[JM0[j]];
      const float* xb = xv[JM1[j]];
      float p = xa[0]*wa.x + xa[1]*wa.y + xa[2]*wa.z + xa[3]*wa.w
              + xb[0]*wb.x + xb[1]*wb.y + xb[2]*wb.z + xb[3]*wb.w;
      p += __shfl_xor(p, 16);
      p += __shfl_xor(p, 8);
      p += __shfl_xor(p, 4);
      p += __shfl_xor(p, 2);
      p += __shfl_xor(p, 1);
      if (og == 0) out[(b0 + elem) * NJ + j] = p + bo[j];
    }
  }
}

extern "C" void kernel_launch(void* const* d_in, const int* in_sizes, int n_in,
                              void* d_out, int out_size, void* d_ws, size_t ws_size,
                              hipStream_t stream) {
  const float* obs = (const float*)d_in[0];
  const float* W1  = (const float*)d_in[1];
  const float* b1  = (const float*)d_in[2];
  const float* W2  = (const float*)d_in[3];
  const float* b2  = (const float*)d_in[4];
  const float* Wm  = (const float*)d_in[5];
  const float* bm  = (const float*)d_in[6];
  const float* Wo  = (const float*)d_in[7];
  const float* bo  = (const float*)d_in[8];
  float* out = (float*)d_out;

  const int B = in_sizes[0] / OBSD;   // 16384
  const int nblk = B / TB;            // 2048

  // pre-pass: split Wmsg into bf16 hi/lo, frag-swizzled (2 MB in d_ws)
  prep_wm<<<2048, 256, 0, stream>>>(Wm, (unsigned*)d_ws);
  gnn_fused<<<nblk, NTHR, 0, stream>>>(obs, W1, b1, W2, b2, bm, Wo, bo,
                                       (const float*)d_ws, out);
}

// Round 6
// 845.205 us; speedup vs baseline: 2.5350x; 1.3513x over previous
//
#include <hip/hip_runtime.h>
#include <math.h>

#define NN   13
#define HH   128
#define NL   8
#define NJ   17
#define OBSD 348
#define DMAX 33
#define TB   8
#define NTHR 512
#define ASTRIDE 264   // shorts per A-plane row = 528 B (16B-aligned rows)
#define HSTRIDE 132   // same row viewed as fp32

// FEAT_IDX table (13 x 33), pad = -1
__constant__ int c_feat[NN * DMAX] = {
  0,1,2,3,4,22,23,24,25,26,27,45,46,47,48,49,50,51,52,53,54,175,176,177,178,179,180,270,271,272,273,274,275,
  5,6,28,29,55,56,57,58,59,60,61,62,63,64,181,182,183,184,185,186,276,277,278,279,280,281,-1,-1,-1,-1,-1,-1,-1,
  7,30,65,66,67,68,69,70,71,72,73,74,187,188,189,190,191,192,253,254,255,282,283,284,285,286,287,-1,-1,-1,-1,-1,-1,
  8,9,10,11,31,32,33,34,75,76,77,78,79,80,81,82,83,84,193,194,195,196,197,198,256,257,258,288,289,290,291,292,293,
  11,34,85,86,87,88,89,90,91,92,93,94,199,200,201,202,203,204,259,294,295,296,297,298,299,-1,-1,-1,-1,-1,-1,-1,-1,
  95,96,97,98,99,100,101,102,103,104,205,206,207,208,209,210,300,301,302,303,304,305,-1,-1,-1,-1,-1,-1,-1,-1,-1,-1,-1,
  12,13,14,15,35,36,37,38,105,106,107,108,109,110,111,112,113,114,211,212,213,214,215,216,260,261,262,306,307,308,309,310,311,
  15,38,115,116,117,118,119,120,121,122,123,124,217,218,219,220,221,222,263,312,313,314,315,316,317,-1,-1,-1,-1,-1,-1,-1,-1,
  125,126,127,128,129,130,131,132,133,134,223,224,225,226,227,228,318,319,320,321,322,323,-1,-1,-1,-1,-1,-1,-1,-1,-1,-1,-1,
  16,17,18,39,40,41,135,136,137,138,139,140,141,142,143,144,229,230,231,232,233,234,264,265,324,325,326,327,328,329,-1,-1,-1,
  18,41,145,146,147,148,149,150,151,152,153,154,235,236,237,238,239,240,266,330,331,332,333,334,335,-1,-1,-1,-1,-1,-1,-1,-1,
  19,20,21,42,43,44,155,156,157,158,159,160,161,162,163,164,241,242,243,244,245,246,267,268,336,337,338,339,340,341,-1,-1,-1,
  21,44,165,166,167,168,169,170,171,172,173,174,247,248,249,250,251,252,269,342,343,344,345,346,347,-1,-1,-1,-1,-1,-1,-1,-1
};

__device__ constexpr int ADJ[NN][3] = {
  {1,9,11},{0,2,0},{1,3,6},{2,4,0},{3,5,0},{4,0,0},{2,7,0},
  {6,8,0},{7,0,0},{0,10,0},{9,0,0},{0,12,0},{11,0,0}
};
__device__ constexpr int DEG[NN] = {3,2,3,2,2,1,2,2,1,2,1,2,1};
__device__ constexpr int JM0[NJ] = {1,1,1,2,2,2,3,2,2,2,6,0,0,9,0,0,11};
__device__ constexpr int JM1[NJ] = {2,2,2,3,3,3,4,6,6,6,7,9,9,10,11,11,12};

typedef float4 F4;
using s8v    = __attribute__((ext_vector_type(8)))  short;   // 8 bf16 (4 VGPR)
using f32x16 = __attribute__((ext_vector_type(16))) float;   // MFMA 32x32 C/D

__device__ __forceinline__ float elu1(float v) { return v > 0.0f ? v : expm1f(v); }

__device__ __forceinline__ unsigned short bf16r(float v) {   // round-to-nearest-even
  unsigned u = __float_as_uint(v);
  unsigned r = u + 0x7FFFu + ((u >> 16) & 1u);
  return (unsigned short)(r >> 16);
}
__device__ __forceinline__ float bf2f(unsigned short s) {
  return __uint_as_float(((unsigned)s) << 16);
}

// ---------------- pre-pass: split+swizzle Wmsg into frag-linear order -------
// ws u32 layout: [l(8)][ks(8)][kind(4: Thi,Tlo,Bhi,Blo)][nt(4)][lane(64)][j2(4)]
// value pair: k = ks*16 + (lane>>5)*8 + 2*j2 ; n = nt*32 + (lane&31)
// EXACT size: 8*8*4*4*64*4 = 262144 u32 = 1 MB -> grid 1024 x 256
__global__ void prep_wm(const float* __restrict__ Wm, unsigned* __restrict__ ws) {
  int i = blockIdx.x * 256 + threadIdx.x;      // 0 .. 262143
  int j2   = i & 3;
  int lane = (i >> 2) & 63;
  int nt   = (i >> 8) & 3;
  int kind = (i >> 10) & 3;
  int ks   = (i >> 12) & 7;
  int l    = i >> 15;                          // 0..7
  int k = ks * 16 + ((lane >> 5) * 8) + 2 * j2;
  int n = nt * 32 + (lane & 31);
  int rbase = (kind >= 2) ? 128 : 0;           // bottom half of Wmsg rows = agg part
  float v0 = Wm[((l * 256) + rbase + k) * HH + n];
  float v1 = Wm[((l * 256) + rbase + k + 1) * HH + n];
  unsigned short a, b;
  if ((kind & 1) == 0) { a = bf16r(v0); b = bf16r(v1); }
  else {
    a = bf16r(v0 - bf2f(bf16r(v0)));
    b = bf16r(v1 - bf2f(bf16r(v1)));
  }
  ws[i] = (unsigned)a | ((unsigned)b << 16);
}

// ---------------- main fused kernel (R3 structure, 512 threads) -------------
__global__ __launch_bounds__(NTHR, 2)
void gnn_fused(const float* __restrict__ obs,
               const float* __restrict__ W1, const float* __restrict__ b1,
               const float* __restrict__ W2, const float* __restrict__ b2,
               const float* __restrict__ bm,
               const float* __restrict__ Wo, const float* __restrict__ bo,
               const float* __restrict__ wmsw,   // pre-swizzled Wmsg
               float* __restrict__ out)
{
  // A-planes: x state, 128 rows (elem*16+node) x [oct(16B): hi 8 | lo 8] bf16
  __shared__ short As[128 * ASTRIDE];      // 67584 B ; aliased as fp32 h scratch
  __shared__ float Bb[2][4096];            // 2 x 16 KB ping-pong -> 100352 B total

  const int t    = threadIdx.x;
  const int wid  = t >> 6;        // wave 0..7
  const int mq   = wid >> 1;      // m-quarter: rows mq*32 .. mq*32+31
  const int nh   = wid & 1;       // n-half
  const int lane = t & 63;
  const int l31  = lane & 31;
  const int lh   = lane >> 5;     // k-half within frag / row-group bit in C
  const bool h1  = (lh == 1);
  const int g    = t >> 5;        // 32-thread group 0..15 (VALU phases)
  const int og   = t & 31;
  const int o0   = og << 2;
  const int b0   = blockIdx.x * TB;

  const F4* wsrc4 = (const F4*)wmsw;
  float* hsc = (float*)As;        // h scratch (row stride HSTRIDE floats)
  F4* bufA = (F4*)Bb;             // 1024 F4
  F4* bufB = ((F4*)Bb) + 1024;
  float* xnb = Bb[1];             // xn gather scratch (3744 floats < 4096)

  // ---------- Phase 0: zero pad rows; gather xn into Bb[1] ----------
  for (int i = t; i < 24 * HSTRIDE; i += NTHR) {   // rows elem*16+{13,14,15}
    int pr = i / HSTRIDE, off = i % HSTRIDE;
    int row = (pr / 3) * 16 + 13 + (pr % 3);
    ((int*)As)[row * HSTRIDE + off] = 0;
  }
  for (int i = t; i < TB * NN * DMAX; i += NTHR) {
    int d  = i % DMAX;
    int r  = i / DMAX;
    int nn = r % NN;
    int bb = r / NN;
    int fi = c_feat[nn * DMAX + d];
    float v = (fi >= 0) ? obs[(b0 + bb) * OBSD + fi] : 0.0f;
    xnb[(bb * NN + nn) * 36 + d] = v;
  }
  __syncthreads();

  // ---------- Phase 1 (VALU): h = elu(xn @ W1 + b1) -> hsc fp32 -------------
  {
    const int n = g;               // 16 groups, 13 active
    if (n < NN) {
      float acc[TB][4];
      const F4 bv = *(const F4*)(b1 + n * HH + o0);
      #pragma unroll
      for (int q = 0; q < TB; ++q) { acc[q][0]=bv.x; acc[q][1]=bv.y; acc[q][2]=bv.z; acc[q][3]=bv.w; }
      #pragma unroll 3
      for (int k = 0; k < DMAX; ++k) {
        const F4 w = *(const F4*)(W1 + (n * DMAX + k) * HH + o0);
        #pragma unroll
        for (int q = 0; q < TB; ++q) {
          const float xv = xnb[(q * NN + n) * 36 + k];
          acc[q][0] += xv * w.x; acc[q][1] += xv * w.y;
          acc[q][2] += xv * w.z; acc[q][3] += xv * w.w;
        }
      }
      #pragma unroll
      for (int q = 0; q < TB; ++q) {
        F4 h;
        h.x = elu1(acc[q][0]); h.y = elu1(acc[q][1]);
        h.z = elu1(acc[q][2]); h.w = elu1(acc[q][3]);
        *(F4*)&hsc[(q * 16 + n) * HSTRIDE + o0] = h;
      }
    }
  }
  __syncthreads();

  // ---------- Phase 2 (VALU): x = h @ W2 + b2 -> regs, then split-store ------
  float xacc[TB][4];
  {
    const int n = g;
    if (n < NN) {
      const F4 bv = *(const F4*)(b2 + n * HH + o0);
      #pragma unroll
      for (int q = 0; q < TB; ++q) {
        xacc[q][0]=bv.x; xacc[q][1]=bv.y; xacc[q][2]=bv.z; xacc[q][3]=bv.w;
      }
      #pragma unroll 2
      for (int k4 = 0; k4 < 32; ++k4) {
        const F4 w0 = *(const F4*)(W2 + (n * HH + k4*4 + 0) * HH + o0);
        const F4 w1 = *(const F4*)(W2 + (n * HH + k4*4 + 1) * HH + o0);
        const F4 w2 = *(const F4*)(W2 + (n * HH + k4*4 + 2) * HH + o0);
        const F4 w3 = *(const F4*)(W2 + (n * HH + k4*4 + 3) * HH + o0);
        #pragma unroll
        for (int q = 0; q < TB; ++q) {
          const F4 hv = *(const F4*)&hsc[(q * 16 + n) * HSTRIDE + k4 * 4];
          xacc[q][0] += hv.x*w0.x + hv.y*w1.x + hv.z*w2.x + hv.w*w3.x;
          xacc[q][1] += hv.x*w0.y + hv.y*w1.y + hv.z*w2.y + hv.w*w3.y;
          xacc[q][2] += hv.x*w0.z + hv.y*w1.z + hv.z*w2.z + hv.w*w3.z;
          xacc[q][3] += hv.x*w0.w + hv.y*w1.w + hv.z*w2.w + hv.w*w3.w;
        }
      }
    }
  }
  __syncthreads();   // all h reads done; safe to overwrite As with x planes
  {
    const int n = g;
    if (n < NN) {
      #pragma unroll
      for (int q = 0; q < TB; ++q) {
        #pragma unroll
        for (int cc = 0; cc < 4; ++cc) {
          float v = xacc[q][cc];
          unsigned short hs = bf16r(v);
          unsigned short ls = bf16r(v - bf2f(hs));
          int col = o0 + cc;
          int ad  = (q * 16 + n) * ASTRIDE + ((col >> 3) << 4) + (col & 7);
          As[ad]     = (short)hs;
          As[ad + 8] = (short)ls;
        }
      }
    }
  }
  __syncthreads();

  // ---------- Phase 3: 8 MFMA layers (R3 staging structure) ------------------
  {
    // prologue: stage chunk 0
    bufA[t] = wsrc4[t]; bufA[t + 512] = wsrc4[t + 512];
    __syncthreads();

    #pragma unroll 1
    for (int l = 0; l < NL; ++l) {
      f32x16 aT[2], aB[2];
      #pragma unroll
      for (int ni = 0; ni < 2; ++ni)
        #pragma unroll
        for (int r = 0; r < 16; ++r) { aT[ni][r] = 0.f; aB[ni][r] = 0.f; }

      #pragma unroll 2
      for (int ks = 0; ks < 8; ++ks) {
        const int gch = l * 8 + ks;          // global chunk index
        F4* cur = (gch & 1) ? bufB : bufA;
        F4* nxt = (gch & 1) ? bufA : bufB;

        F4 r0, r1;
        const bool more = (gch < NL * 8 - 1);
        if (more) {
          const F4* s = wsrc4 + (size_t)(gch + 1) * 1024;
          r0 = s[t]; r1 = s[t + 512];
        }

        const short* bb = (const short*)cur;
        s8v ah, al;
        {
          const int row = mq * 32 + l31;
          const short* ap = As + row * ASTRIDE + (2 * ks + lh) * 16;
          ah = *(const s8v*)ap;
          al = *(const s8v*)(ap + 8);
        }
        s8v bth[2], btl[2], bbh[2], bbl[2];
        #pragma unroll
        for (int ni = 0; ni < 2; ++ni) {
          const int ntab = nh * 2 + ni;
          bth[ni] = *(const s8v*)(bb + ((0 * 4 + ntab) * 64 + lane) * 8);
          btl[ni] = *(const s8v*)(bb + ((1 * 4 + ntab) * 64 + lane) * 8);
          bbh[ni] = *(const s8v*)(bb + ((2 * 4 + ntab) * 64 + lane) * 8);
          bbl[ni] = *(const s8v*)(bb + ((3 * 4 + ntab) * 64 + lane) * 8);
        }
        #pragma unroll
        for (int ni = 0; ni < 2; ++ni) {
          aT[ni] = __builtin_amdgcn_mfma_f32_32x32x16_bf16(ah, bth[ni], aT[ni], 0, 0, 0);
          aT[ni] = __builtin_amdgcn_mfma_f32_32x32x16_bf16(ah, btl[ni], aT[ni], 0, 0, 0);
          aT[ni] = __builtin_amdgcn_mfma_f32_32x32x16_bf16(al, bth[ni], aT[ni], 0, 0, 0);
          aB[ni] = __builtin_amdgcn_mfma_f32_32x32x16_bf16(ah, bbh[ni], aB[ni], 0, 0, 0);
          aB[ni] = __builtin_amdgcn_mfma_f32_32x32x16_bf16(ah, bbl[ni], aB[ni], 0, 0, 0);
          aB[ni] = __builtin_amdgcn_mfma_f32_32x32x16_bf16(al, bbh[ni], aB[ni], 0, 0, 0);
        }

        if (more) { nxt[t] = r0; nxt[t + 512] = r1; }
        __syncthreads();   // publishes nxt; guards cur reuse and A-row overwrite
      }

      // epilogue: x_new = elu(Y_top + N*Y_bot + bias) ; split-store to As
      #pragma unroll
      for (int ni = 0; ni < 2; ++ni) {
        const int col  = (nh * 2 + ni) * 32 + l31;
        const float bias = bm[l * HH + col];
        float cb[16], sw[16];
        #pragma unroll
        for (int r = 0; r < 16; ++r) { cb[r] = aB[ni][r]; sw[r] = __shfl_xor(cb[r], 32); }

        #pragma unroll
        for (int r = 0; r < 16; ++r) {
          const int p  = (r & 3) + 8 * (r >> 2);
          const int n0 = p & 15;            // node for lane-half 0 (always < 13)
          const int n1 = n0 + 4;            // node for lane-half 1 (may be pad)
          const int es = p >> 4;
          #define SRCV(np)                                                \
            ({ const int rl = (es << 4) + (np);                           \
               const int hp = (rl >> 2) & 1;                              \
               const int pp = rl - 4 * hp;                                \
               const int rp = (pp & 3) + 4 * (pp >> 3);                   \
               (hp == 1) ? (h1 ? cb[rp] : sw[rp])                         \
                         : (h1 ? sw[rp] : cb[rp]); })
          float a0 = SRCV(ADJ[n0][0]);
          if (DEG[n0] > 1) a0 += SRCV(ADJ[n0][1]);
          if (DEG[n0] > 2) a0 += SRCV(ADJ[n0][2]);
          float a1 = 0.f;
          if (n1 < NN) {
            a1 = SRCV(ADJ[n1][0]);
            if (DEG[n1] > 1) a1 += SRCV(ADJ[n1][1]);
            if (DEG[n1] > 2) a1 += SRCV(ADJ[n1][2]);
          }
          #undef SRCV
          const float agg = h1 ? a1 : a0;
          const float tot = aT[ni][r] + agg + bias;
          float xv = elu1(tot);
          if (n1 >= NN) xv = h1 ? 0.f : xv;     // pad rows stay zero (stored)
          unsigned short hs = bf16r(xv);
          unsigned short ls = bf16r(xv - bf2f(hs));
          const int row = mq * 32 + p + 4 * lh;
          const int ad  = row * ASTRIDE + ((col >> 3) << 4) + (col & 7);
          As[ad]     = (short)hs;
          As[ad + 8] = (short)ls;
        }
      }
      __syncthreads();
    }
  }

  // ---------- Phase 4: readout ----------------------------------------------
  if (g < TB) {
    const int elem = g;          // 0..7
    const int c = og * 4;        // 4 channels per thread
    float xv[NN][4];
    #pragma unroll
    for (int n = 0; n < NN; ++n) {
      const int ad = (elem * 16 + n) * ASTRIDE + ((c >> 3) << 4) + (c & 7);
      const ushort4 uh = *(const ushort4*)(As + ad);
      const ushort4 ul = *(const ushort4*)(As + ad + 8);
      xv[n][0] = bf2f(uh.x) + bf2f(ul.x);
      xv[n][1] = bf2f(uh.y) + bf2f(ul.y);
      xv[n][2] = bf2f(uh.z) + bf2f(ul.z);
      xv[n][3] = bf2f(uh.w) + bf2f(ul.w);
    }
    #pragma unroll
    for (int j = 0; j < NJ; ++j) {
      const F4 wa = *(const F4*)(Wo + j * 256 + c);
      const F4 wb = *(const F4*)(Wo + j * 256 + 128 + c);
      const float* xa = xv[JM0[j]];
      const float* xb = xv[JM1[j]];
      float p = xa[0]*wa.x + xa[1]*wa.y + xa[2]*wa.z + xa[3]*wa.w
              + xb[0]*wb.x + xb[1]*wb.y + xb[2]*wb.z + xb[3]*wb.w;
      p += __shfl_xor(p, 16);
      p += __shfl_xor(p, 8);
      p += __shfl_xor(p, 4);
      p += __shfl_xor(p, 2);
      p += __shfl_xor(p, 1);
      if (og == 0) out[(b0 + elem) * NJ + j] = p + bo[j];
    }
  }
}

extern "C" void kernel_launch(void* const* d_in, const int* in_sizes, int n_in,
                              void* d_out, int out_size, void* d_ws, size_t ws_size,
                              hipStream_t stream) {
  const float* obs = (const float*)d_in[0];
  const float* W1  = (const float*)d_in[1];
  const float* b1  = (const float*)d_in[2];
  const float* W2  = (const float*)d_in[3];
  const float* b2  = (const float*)d_in[4];
  const float* Wm  = (const float*)d_in[5];
  const float* bm  = (const float*)d_in[6];
  const float* Wo  = (const float*)d_in[7];
  const float* bo  = (const float*)d_in[8];
  float* out = (float*)d_out;

  const int B = in_sizes[0] / OBSD;   // 16384
  const int nblk = B / TB;            // 2048

  // pre-pass: split Wmsg into bf16 hi/lo, frag-swizzled (exactly 1 MB in d_ws)
  prep_wm<<<1024, 256, 0, stream>>>(Wm, (unsigned*)d_ws);
  gnn_fused<<<nblk, NTHR, 0, stream>>>(obs, W1, b1, W2, b2, bm, Wo, bo,
                                       (const float*)d_ws, out);
}